// Round 1
// baseline (949.096 us; speedup 1.0000x reference)
//
#include <hip/hip_runtime.h>

#define NN 100000
#define BQ 1024
#define EE 262144
#define KTOP 20

typedef unsigned long long ull;

__device__ __forceinline__ ull enc64(double d) {
  ull u = (ull)__double_as_longlong(d);
  return (u >> 63) ? ~u : (u | 0x8000000000000000ull);
}
__device__ __forceinline__ double dec64(ull u) {
  ull b = (u >> 63) ? (u & 0x7FFFFFFFFFFFFFFFull) : ~u;
  return __longlong_as_double((long long)b);
}

// ---------------- init ----------------
__global__ void k_init(ull* __restrict__ menc, double* __restrict__ s,
                       float* __restrict__ appears, float* __restrict__ out_score) {
  int i = blockIdx.x * 256 + threadIdx.x;
  int st = gridDim.x * 256;
  for (int n = i; n < NN; n += st) {
    menc[n] = 0ull;      // encodes "below every real value"
    s[n] = 0.0;
    appears[n] = 0.f;
    out_score[n] = 0.f;
  }
}

// ---------------- M = Wq^T Wk (f64 acc, f32 store) ----------------
__global__ void k_matM(const float* __restrict__ Wq, const float* __restrict__ Wk,
                       float* __restrict__ M) {
  int x = blockIdx.x;
  int y = blockIdx.y * 256 + threadIdx.x;
  double acc = 0.0;
  for (int a = 0; a < 512; a++)
    acc += (double)Wq[a * 512 + x] * (double)Wk[a * 512 + y];
  M[x * 512 + y] = (float)acc;
}

__global__ void k_transpose(const float* __restrict__ M, float* __restrict__ MT) {
  int x = blockIdx.x;
  int y = blockIdx.y * 256 + threadIdx.x;
  MT[y * 512 + x] = M[x * 512 + y];
}

// pack Wnode[k][0:128]=M00[k][*], [128:256]=M01[k][*], [256:384]=M10^T[k][*]
__global__ void k_pack(const float* __restrict__ M, float* __restrict__ Wnode) {
  int idx = blockIdx.x * 256 + threadIdx.x;
  if (idx >= 128 * 384) return;
  int k = idx / 384, c = idx - k * 384;
  Wnode[idx] = (c < 256) ? M[k * 512 + c] : M[(128 + (c - 256)) * 512 + k];
}

// ---------------- per-query vectors ----------------
// Qv[b][0:128]=u_h (dot h_vj), [128:256]=u_i (dot h_vi), [256:384]=u_r (dot r); cq[b] scalar
__global__ void k_pq(const float* __restrict__ M, const float* __restrict__ MT,
                     const float* __restrict__ qsA, const float* __restrict__ qrA,
                     float* __restrict__ Qv, double* __restrict__ cq) {
  int b = blockIdx.x, d = threadIdx.x;  // 128 threads
  __shared__ float qs[128], qr[128];
  qs[d] = qsA[b * 128 + d];
  qr[d] = qrA[b * 128 + d];
  __syncthreads();
  double uh = 0, ui = 0, ur = 0;
  for (int x = 0; x < 128; x++) {
    double qsx = qs[x], qrx = qr[x];
    uh += qsx * (double)M[(256 + x) * 512 + d]        + qrx * (double)M[(384 + x) * 512 + d];
    ur += qsx * (double)M[(256 + x) * 512 + 128 + d]  + qrx * (double)M[(384 + x) * 512 + 128 + d];
    ui += qsx * (double)MT[(256 + x) * 512 + d]       + qrx * (double)MT[(384 + x) * 512 + d];
    ur += qsx * (double)MT[(256 + x) * 512 + 128 + d] + qrx * (double)MT[(384 + x) * 512 + 128 + d];
  }
  Qv[b * 384 + d]       = (float)uh;
  Qv[b * 384 + 128 + d] = (float)ui;
  Qv[b * 384 + 256 + d] = (float)ur;
  double t1 = 0, t2 = 0;
  for (int y = 0; y < 128; y++) {
    double qsy = qs[y], qry = qr[y];
    t1 += qsy * (double)MT[(256 + y) * 512 + 256 + d] + qry * (double)MT[(384 + y) * 512 + 256 + d];
    t2 += qsy * (double)MT[(256 + y) * 512 + 384 + d] + qry * (double)MT[(384 + y) * 512 + 384 + d];
  }
  double cp = (double)qs[d] * t1 + (double)qr[d] * t2;
  for (int off = 32; off; off >>= 1) cp += __shfl_down(cp, off, 64);
  __shared__ double red[2];
  if ((d & 63) == 0) red[d >> 6] = cp;
  __syncthreads();
  if (d == 0) cq[b] = red[0] + red[1];
}

// ---------------- node transforms: T = node_repr @ Wnode (128x384), f64 acc ----------------
__global__ __launch_bounds__(512) void k_gemm_node(const float* __restrict__ A,
                                                   const float* __restrict__ Wnode,
                                                   float* __restrict__ T) {
  __shared__ __align__(16) float As[128][132];
  __shared__ __align__(16) float Bs[128][128];
  int t = threadIdx.x;
  int row0 = blockIdx.x * 128;
  int panel = blockIdx.y;  // 0..2
#pragma unroll
  for (int i = 0; i < 8; i++) {
    int fi = t + i * 512;
    int r = fi >> 5, c4 = (fi & 31) * 4;
    float4 v = make_float4(0.f, 0.f, 0.f, 0.f);
    if (row0 + r < NN) v = *(const float4*)(A + (size_t)(row0 + r) * 128 + c4);
    *(float4*)&As[r][c4] = v;
    *(float4*)&Bs[r][c4] = *(const float4*)(Wnode + r * 384 + panel * 128 + c4);
  }
  __syncthreads();
  int cg = t & 15, rg = t >> 4;
  int c8 = cg * 8, r4 = rg * 4;
  double acc[4][8];
#pragma unroll
  for (int i = 0; i < 4; i++)
#pragma unroll
    for (int j = 0; j < 8; j++) acc[i][j] = 0.0;
#pragma unroll 2
  for (int k = 0; k < 128; k++) {
    float bv[8];
    *(float4*)&bv[0] = *(const float4*)&Bs[k][c8];
    *(float4*)&bv[4] = *(const float4*)&Bs[k][c8 + 4];
    float av[4];
#pragma unroll
    for (int i = 0; i < 4; i++) av[i] = As[r4 + i][k];
#pragma unroll
    for (int i = 0; i < 4; i++) {
      double ad = (double)av[i];
#pragma unroll
      for (int j = 0; j < 8; j++) acc[i][j] += ad * (double)bv[j];
    }
  }
#pragma unroll
  for (int i = 0; i < 4; i++) {
    int r = row0 + r4 + i;
    if (r < NN) {
      float o[8];
#pragma unroll
      for (int j = 0; j < 8; j++) o[j] = (float)acc[i][j];
      float* dst = T + (size_t)r * 384 + panel * 128 + c8;
      *(float4*)&dst[0] = *(float4*)&o[0];
      *(float4*)&dst[4] = *(float4*)&o[4];
    }
  }
}

// ---------------- q11[e] = r_e^T M11 r_e, f64 acc ----------------
__global__ __launch_bounds__(512) void k_q11(const float* __restrict__ rel,
                                             const float* __restrict__ M,
                                             double* __restrict__ q11) {
  __shared__ __align__(16) float Rt[128][132];
  __shared__ __align__(16) float Ms[128][128];
  int t = threadIdx.x;
  int e0 = blockIdx.x * 128;
#pragma unroll
  for (int i = 0; i < 8; i++) {
    int fi = t + i * 512;
    int r = fi >> 5, c4 = (fi & 31) * 4;
    *(float4*)&Rt[r][c4] = *(const float4*)(rel + (size_t)(e0 + r) * 128 + c4);
    *(float4*)&Ms[r][c4] = *(const float4*)(M + (size_t)(128 + r) * 512 + 128 + c4);
  }
  __syncthreads();
  int cg = t & 15, eg2 = t >> 4;
  int c8 = cg * 8, r4 = eg2 * 4;
  double acc[4][8];
#pragma unroll
  for (int i = 0; i < 4; i++)
#pragma unroll
    for (int j = 0; j < 8; j++) acc[i][j] = 0.0;
#pragma unroll 2
  for (int k = 0; k < 128; k++) {
    float bv[8];
    *(float4*)&bv[0] = *(const float4*)&Ms[k][c8];
    *(float4*)&bv[4] = *(const float4*)&Ms[k][c8 + 4];
    float av[4];
#pragma unroll
    for (int i = 0; i < 4; i++) av[i] = Rt[r4 + i][k];
#pragma unroll
    for (int i = 0; i < 4; i++) {
      double ad = (double)av[i];
#pragma unroll
      for (int j = 0; j < 8; j++) acc[i][j] += ad * (double)bv[j];
    }
  }
  double p[4];
#pragma unroll
  for (int i = 0; i < 4; i++) {
    double sum = 0.0;
#pragma unroll
    for (int j = 0; j < 8; j++) sum += acc[i][j] * (double)Rt[r4 + i][c8 + j];
    p[i] = sum;
  }
#pragma unroll
  for (int i = 0; i < 4; i++)
    for (int off = 8; off; off >>= 1) p[i] += __shfl_down(p[i], off, 16);
  if (cg == 0) {
#pragma unroll
    for (int i = 0; i < 4; i++) q11[e0 + r4 + i] = p[i];
  }
}

// ---------------- per-edge logits (one wave per edge, grid-stride) + segment max ----------------
__global__ void k_logits(const int* __restrict__ edges, const float* __restrict__ nrep,
                         const float* __restrict__ rel, const float* __restrict__ T,
                         const float* __restrict__ Qv, const double* __restrict__ cq,
                         const double* __restrict__ q11, double* __restrict__ logits,
                         ull* __restrict__ menc) {
  int lane = threadIdx.x & 63;
  int wid = blockIdx.x * (blockDim.x >> 6) + (threadIdx.x >> 6);
  int nw = gridDim.x * (blockDim.x >> 6);
  for (int e = wid; e < EE; e += nw) {
    int eg = edges[(size_t)e * 8 + 0];
    int vi = edges[(size_t)e * 8 + 6];
    int vj = edges[(size_t)e * 8 + 7];
    const float* Tvi = T + (size_t)vi * 384;
    const float* Tvj = T + (size_t)vj * 384;
    const float* q = Qv + (size_t)eg * 384;
    const float* hi = nrep + (size_t)vi * 128;
    const float* hj = nrep + (size_t)vj * 128;
    const float* re = rel + (size_t)e * 128;
    int d0 = lane * 2;
    float2 g   = *(const float2*)&Tvi[d0];
    float2 h1  = *(const float2*)&Tvi[128 + d0];
    float2 jj  = *(const float2*)&Tvj[256 + d0];
    float2 uh  = *(const float2*)&q[d0];
    float2 uiq = *(const float2*)&q[128 + d0];
    float2 urq = *(const float2*)&q[256 + d0];
    float2 hvi = *(const float2*)&hi[d0];
    float2 hvj = *(const float2*)&hj[d0];
    float2 rr  = *(const float2*)&re[d0];
    double v = ((double)g.x + (double)uh.x) * (double)hvj.x
             + ((double)g.y + (double)uh.y) * (double)hvj.y
             + (double)uiq.x * (double)hvi.x + (double)uiq.y * (double)hvi.y
             + ((double)h1.x + (double)jj.x + (double)urq.x) * (double)rr.x
             + ((double)h1.y + (double)jj.y + (double)urq.y) * (double)rr.y;
    for (int off = 32; off; off >>= 1) v += __shfl_down(v, off, 64);
    if (lane == 0) {
      double l = v + cq[eg] + q11[e];
      logits[e] = l;
      atomicMax(&menc[vi], enc64(l));
    }
  }
}

// ---------------- exp + segment sum ----------------
__global__ void k_exp(const int* __restrict__ edges, const ull* __restrict__ menc,
                      const double* __restrict__ logits, double* __restrict__ ex,
                      double* __restrict__ s) {
  int i = blockIdx.x * 256 + threadIdx.x;
  int st = gridDim.x * 256;
  for (int e = i; e < EE; e += st) {
    int vi = edges[(size_t)e * 8 + 6];
    double m = dec64(menc[vi]);
    double v = exp(logits[e] - m);
    ex[e] = v;
    atomicAdd(&s[vi], v);
  }
}

// ---------------- sm + target ----------------
__global__ void k_smt(const int* __restrict__ edges, const double* __restrict__ s,
                      const double* __restrict__ ex, const float* __restrict__ nscore,
                      double* __restrict__ smv, double* __restrict__ target) {
  int i = blockIdx.x * 256 + threadIdx.x;
  int st = gridDim.x * 256;
  for (int e = i; e < EE; e += st) {
    int vi = edges[(size_t)e * 8 + 6];
    double sm = ex[e] / s[vi];
    smv[e] = sm;
    target[e] = sm * (double)nscore[vi];
  }
}

__global__ void k_zero_agg(float* __restrict__ agg) {
  long long i = (long long)blockIdx.x * 256 + threadIdx.x;
  long long st = (long long)gridDim.x * 256;
  for (long long n = i; n < (long long)NN * 128; n += st) agg[n] = 0.f;
}

// ---------------- top-20 per query (jax tie-break: lower index) + scatter ----------------
__global__ void k_topk(const double* __restrict__ target, const double* __restrict__ smv,
                       const int* __restrict__ edges, const float* __restrict__ nrep,
                       float* __restrict__ out_score, float* __restrict__ agg,
                       float* __restrict__ appears) {
  int b = blockIdx.x, t = threadIdx.x;  // 256 threads
  __shared__ double sv[256];
  __shared__ int si[256];
  __shared__ int winners[KTOP];
  double v = target[b * 256 + t];
  for (int k = 0; k < KTOP; k++) {
    sv[t] = v;
    si[t] = t;
    __syncthreads();
    for (int s2 = 128; s2 > 0; s2 >>= 1) {
      if (t < s2) {
        double ov = sv[t + s2];
        int oi = si[t + s2];
        if (ov > sv[t] || (ov == sv[t] && oi < si[t])) { sv[t] = ov; si[t] = oi; }
      }
      __syncthreads();
    }
    int w = si[0];
    if (t == 0) winners[k] = w;
    if (t == w) v = -1.0;  // targets are >= 0
    __syncthreads();
  }
  for (int k = 0; k < KTOP; k++) {
    int e = b * 256 + winners[k];
    int vi = edges[(size_t)e * 8 + 6];
    int vj = edges[(size_t)e * 8 + 7];
    if (t < 128) {
      float smf = (float)smv[e];
      atomicAdd(&agg[(size_t)vi * 128 + t], smf * nrep[(size_t)vj * 128 + t]);
    } else if (t == 128) {
      atomicAdd(&out_score[vj], (float)target[e]);
    } else if (t == 129) {
      appears[vi] = 1.f;
    }
  }
}

// ---------------- final: leaky_relu((agg + coef*h) @ W_lin^T + b) ----------------
__global__ __launch_bounds__(512) void k_final(const float* __restrict__ agg,
                                               const float* __restrict__ appears,
                                               const float* __restrict__ nrep,
                                               const float* __restrict__ Wl,
                                               const float* __restrict__ bl,
                                               float* __restrict__ outr) {
  __shared__ __align__(16) float Xs[128][132];
  __shared__ __align__(16) float Ws[128][132];  // Ws[k][j] = Wl[j][k]
  int t = threadIdx.x;
  int row0 = blockIdx.x * 128;
#pragma unroll
  for (int i = 0; i < 8; i++) {
    int fi = t + i * 512;
    int r = fi >> 5, c4 = (fi & 31) * 4;
    int rr = row0 + r;
    float4 v = make_float4(0.f, 0.f, 0.f, 0.f);
    if (rr < NN) {
      float4 ag = *(const float4*)(agg + (size_t)rr * 128 + c4);
      float4 h = *(const float4*)(nrep + (size_t)rr * 128 + c4);
      float coef = (appears[rr] > 0.f) ? 0.f : 1.f;  // RATIO = 0
      v.x = ag.x + coef * h.x;
      v.y = ag.y + coef * h.y;
      v.z = ag.z + coef * h.z;
      v.w = ag.w + coef * h.w;
    }
    *(float4*)&Xs[r][c4] = v;
    float4 w = *(const float4*)(Wl + r * 128 + c4);  // row j=r, cols k=c4..c4+3
    Ws[c4 + 0][r] = w.x;
    Ws[c4 + 1][r] = w.y;
    Ws[c4 + 2][r] = w.z;
    Ws[c4 + 3][r] = w.w;
  }
  __syncthreads();
  int cg = t & 15, rg = t >> 4;
  int c8 = cg * 8, r4 = rg * 4;
  float acc[4][8];
#pragma unroll
  for (int i = 0; i < 4; i++)
#pragma unroll
    for (int j = 0; j < 8; j++) acc[i][j] = 0.f;
#pragma unroll 4
  for (int k = 0; k < 128; k++) {
    float bv[8];
    *(float4*)&bv[0] = *(const float4*)&Ws[k][c8];
    *(float4*)&bv[4] = *(const float4*)&Ws[k][c8 + 4];
    float av[4];
#pragma unroll
    for (int i = 0; i < 4; i++) av[i] = Xs[r4 + i][k];
#pragma unroll
    for (int i = 0; i < 4; i++)
#pragma unroll
      for (int j = 0; j < 8; j++) acc[i][j] += av[i] * bv[j];
  }
#pragma unroll
  for (int i = 0; i < 4; i++) {
    int r = row0 + r4 + i;
    if (r < NN) {
      float o[8];
#pragma unroll
      for (int j = 0; j < 8; j++) {
        float y = acc[i][j] + bl[c8 + j];
        o[j] = (y > 0.f) ? y : 0.01f * y;
      }
      float* dst = outr + (size_t)r * 128 + c8;
      *(float4*)&dst[0] = *(float4*)&o[0];
      *(float4*)&dst[4] = *(float4*)&o[4];
    }
  }
}

extern "C" void kernel_launch(void* const* d_in, const int* in_sizes, int n_in,
                              void* d_out, int out_size, void* d_ws, size_t ws_size,
                              hipStream_t stream) {
  const float* node_score = (const float*)d_in[0];
  const float* node_repr  = (const float*)d_in[1];
  const float* rel_emb    = (const float*)d_in[2];
  const float* q_src      = (const float*)d_in[3];
  const float* q_rel      = (const float*)d_in[4];
  const float* Wq         = (const float*)d_in[5];
  const float* Wk         = (const float*)d_in[6];
  const float* W_lin      = (const float*)d_in[7];
  const float* b_lin      = (const float*)d_in[8];
  const int*   edges      = (const int*)d_in[9];

  char* ws = (char*)d_ws;
  size_t off = 0;
  auto carve = [&](size_t bytes) -> void* {
    void* p = ws + off;
    off += (bytes + 255) & ~(size_t)255;
    return p;
  };
  float*  M      = (float*)carve(512 * 512 * 4);
  float*  MT     = (float*)carve(512 * 512 * 4);
  float*  Wnode  = (float*)carve(128 * 384 * 4);
  float*  Qv     = (float*)carve((size_t)BQ * 384 * 4);
  double* cq     = (double*)carve((size_t)BQ * 8);
  double* logits = (double*)carve((size_t)EE * 8);
  double* q11    = (double*)carve((size_t)EE * 8);
  ull*    menc   = (ull*)carve((size_t)NN * 8);
  double* s      = (double*)carve((size_t)NN * 8);
  double* ex     = (double*)carve((size_t)EE * 8);
  double* smv    = (double*)carve((size_t)EE * 8);
  double* target = (double*)carve((size_t)EE * 8);
  float*  appears= (float*)carve((size_t)NN * 4);
  float*  T      = (float*)carve((size_t)NN * 384 * 4);
  float*  agg    = T;  // alias: T dead after k_logits, agg needed after

  float* out_score = (float*)d_out;
  float* out_repr  = (float*)d_out + NN;

  k_init<<<512, 256, 0, stream>>>(menc, s, appears, out_score);
  k_matM<<<dim3(512, 2), 256, 0, stream>>>(Wq, Wk, M);
  k_transpose<<<dim3(512, 2), 256, 0, stream>>>(M, MT);
  k_pack<<<192, 256, 0, stream>>>(M, Wnode);
  k_pq<<<BQ, 128, 0, stream>>>(M, MT, q_src, q_rel, Qv, cq);
  k_gemm_node<<<dim3(782, 3), 512, 0, stream>>>(node_repr, Wnode, T);
  k_q11<<<2048, 512, 0, stream>>>(rel_emb, M, q11);
  k_logits<<<2048, 256, 0, stream>>>(edges, node_repr, rel_emb, T, Qv, cq, q11, logits, menc);
  k_exp<<<1024, 256, 0, stream>>>(edges, menc, logits, ex, s);
  k_smt<<<1024, 256, 0, stream>>>(edges, s, ex, node_score, smv, target);
  k_zero_agg<<<2048, 256, 0, stream>>>(agg);
  k_topk<<<BQ, 256, 0, stream>>>(target, smv, edges, node_repr, out_score, agg, appears);
  k_final<<<782, 512, 0, stream>>>(agg, appears, node_repr, W_lin, b_lin, out_repr);
}

// Round 2
// 720.116 us; speedup vs baseline: 1.3180x; 1.3180x over previous
//
#include <hip/hip_runtime.h>

#define NN 100000
#define BQ 1024
#define EE 262144
#define KTOP 20

typedef unsigned long long ull;

__device__ __forceinline__ ull enc64(double d) {
  ull u = (ull)__double_as_longlong(d);
  return (u >> 63) ? ~u : (u | 0x8000000000000000ull);
}
__device__ __forceinline__ double dec64(ull u) {
  ull b = (u >> 63) ? (u & 0x7FFFFFFFFFFFFFFFull) : ~u;
  return __longlong_as_double((long long)b);
}

// ---------------- init ----------------
__global__ void k_init(ull* __restrict__ menc, double* __restrict__ s,
                       float* __restrict__ appears, float* __restrict__ out_score) {
  int i = blockIdx.x * 256 + threadIdx.x;
  int st = gridDim.x * 256;
  for (int n = i; n < NN; n += st) {
    menc[n] = 0ull;  // below every real encoding
    s[n] = 0.0;
    appears[n] = 0.f;
    out_score[n] = 0.f;
  }
}

// ---------------- M = Wq^T Wk (f64 acc, f32 store) ----------------
__global__ void k_matM(const float* __restrict__ Wq, const float* __restrict__ Wk,
                       float* __restrict__ M) {
  int x = blockIdx.x;
  int y = blockIdx.y * 256 + threadIdx.x;
  double acc = 0.0;
  for (int a = 0; a < 512; a++)
    acc += (double)Wq[a * 512 + x] * (double)Wk[a * 512 + y];
  M[x * 512 + y] = (float)acc;
}

__global__ void k_transpose(const float* __restrict__ M, float* __restrict__ MT) {
  int x = blockIdx.x;
  int y = blockIdx.y * 256 + threadIdx.x;
  MT[y * 512 + x] = M[x * 512 + y];
}

// pack Wnode[k][0:128]=M00[k][*], [128:256]=M01[k][*], [256:384]=M10^T[k][*]
// plus WlT[k][j] = W_lin[j][k]
__global__ void k_pack(const float* __restrict__ M, const float* __restrict__ Wl,
                       float* __restrict__ Wnode, float* __restrict__ WlT) {
  int idx = blockIdx.x * 256 + threadIdx.x;
  if (idx < 128 * 384) {
    int k = idx / 384, c = idx - k * 384;
    Wnode[idx] = (c < 256) ? M[k * 512 + c] : M[(128 + (c - 256)) * 512 + k];
  } else if (idx < 128 * 384 + 128 * 128) {
    int j = idx - 128 * 384;
    int k = j >> 7, c = j & 127;
    WlT[j] = Wl[c * 128 + k];
  }
}

// ---------------- per-query vectors (f64 acc) ----------------
__global__ void k_pq(const float* __restrict__ M, const float* __restrict__ MT,
                     const float* __restrict__ qsA, const float* __restrict__ qrA,
                     float* __restrict__ Qv, double* __restrict__ cq) {
  int b = blockIdx.x, d = threadIdx.x;  // 128 threads
  __shared__ float qs[128], qr[128];
  qs[d] = qsA[b * 128 + d];
  qr[d] = qrA[b * 128 + d];
  __syncthreads();
  double uh = 0, ui = 0, ur = 0;
  for (int x = 0; x < 128; x++) {
    double qsx = qs[x], qrx = qr[x];
    uh += qsx * (double)M[(256 + x) * 512 + d]        + qrx * (double)M[(384 + x) * 512 + d];
    ur += qsx * (double)M[(256 + x) * 512 + 128 + d]  + qrx * (double)M[(384 + x) * 512 + 128 + d];
    ui += qsx * (double)MT[(256 + x) * 512 + d]       + qrx * (double)MT[(384 + x) * 512 + d];
    ur += qsx * (double)MT[(256 + x) * 512 + 128 + d] + qrx * (double)MT[(384 + x) * 512 + 128 + d];
  }
  Qv[b * 384 + d]       = (float)uh;
  Qv[b * 384 + 128 + d] = (float)ui;
  Qv[b * 384 + 256 + d] = (float)ur;
  double t1 = 0, t2 = 0;
  for (int y = 0; y < 128; y++) {
    double qsy = qs[y], qry = qr[y];
    t1 += qsy * (double)MT[(256 + y) * 512 + 256 + d] + qry * (double)MT[(384 + y) * 512 + 256 + d];
    t2 += qsy * (double)MT[(256 + y) * 512 + 384 + d] + qry * (double)MT[(384 + y) * 512 + 384 + d];
  }
  double cp = (double)qs[d] * t1 + (double)qr[d] * t2;
  for (int off = 32; off; off >>= 1) cp += __shfl_down(cp, off, 64);
  __shared__ double red[2];
  if ((d & 63) == 0) red[d >> 6] = cp;
  __syncthreads();
  if (d == 0) cq[b] = red[0] + red[1];
}

// ---------------- T = node_repr @ Wnode, f32 acc, A-only LDS ----------------
__global__ __launch_bounds__(256, 4) void k_gemm_node(const float* __restrict__ A,
                                                      const float* __restrict__ Wnode,
                                                      float* __restrict__ T) {
  __shared__ __align__(16) float As[64][132];
  int t = threadIdx.x;
  int row0 = blockIdx.x * 64;
  int panel = blockIdx.y;  // 0..2
#pragma unroll
  for (int i = 0; i < 8; i++) {
    int fi = t + i * 256;
    int r = fi >> 5, c4 = (fi & 31) * 4;
    float4 v = make_float4(0.f, 0.f, 0.f, 0.f);
    if (row0 + r < NN) v = *(const float4*)(A + (size_t)(row0 + r) * 128 + c4);
    *(float4*)&As[r][c4] = v;
  }
  __syncthreads();
  int cg = t & 15, rg = t >> 4;
  int c8 = cg * 8, r4 = rg * 4;
  const float* Bp = Wnode + panel * 128 + c8;
  float acc[4][8];
#pragma unroll
  for (int i = 0; i < 4; i++)
#pragma unroll
    for (int j = 0; j < 8; j++) acc[i][j] = 0.f;
#pragma unroll 4
  for (int k = 0; k < 128; k++) {
    float4 b0 = *(const float4*)(Bp + (size_t)k * 384);
    float4 b1 = *(const float4*)(Bp + (size_t)k * 384 + 4);
    float bv[8] = {b0.x, b0.y, b0.z, b0.w, b1.x, b1.y, b1.z, b1.w};
    float av[4];
#pragma unroll
    for (int i = 0; i < 4; i++) av[i] = As[r4 + i][k];
#pragma unroll
    for (int i = 0; i < 4; i++)
#pragma unroll
      for (int j = 0; j < 8; j++) acc[i][j] += av[i] * bv[j];
  }
#pragma unroll
  for (int i = 0; i < 4; i++) {
    int r = row0 + r4 + i;
    if (r < NN) {
      float* dst = T + (size_t)r * 384 + panel * 128 + c8;
      *(float4*)&dst[0] = make_float4(acc[i][0], acc[i][1], acc[i][2], acc[i][3]);
      *(float4*)&dst[4] = make_float4(acc[i][4], acc[i][5], acc[i][6], acc[i][7]);
    }
  }
}

// ---------------- q11[e] = r_e^T M11 r_e, f32 acc, R-only LDS ----------------
__global__ __launch_bounds__(256, 4) void k_q11(const float* __restrict__ rel,
                                                const float* __restrict__ M,
                                                float* __restrict__ q11) {
  __shared__ __align__(16) float Rt[64][132];
  int t = threadIdx.x;
  int e0 = blockIdx.x * 64;
#pragma unroll
  for (int i = 0; i < 8; i++) {
    int fi = t + i * 256;
    int r = fi >> 5, c4 = (fi & 31) * 4;
    *(float4*)&Rt[r][c4] = *(const float4*)(rel + (size_t)(e0 + r) * 128 + c4);
  }
  __syncthreads();
  int cg = t & 15, rg = t >> 4;
  int c8 = cg * 8, r4 = rg * 4;
  const float* Mp = M + (size_t)128 * 512 + 128 + c8;  // M11 row 0, this col-slice
  float acc[4][8];
#pragma unroll
  for (int i = 0; i < 4; i++)
#pragma unroll
    for (int j = 0; j < 8; j++) acc[i][j] = 0.f;
#pragma unroll 4
  for (int k = 0; k < 128; k++) {
    float4 b0 = *(const float4*)(Mp + (size_t)k * 512);
    float4 b1 = *(const float4*)(Mp + (size_t)k * 512 + 4);
    float bv[8] = {b0.x, b0.y, b0.z, b0.w, b1.x, b1.y, b1.z, b1.w};
    float av[4];
#pragma unroll
    for (int i = 0; i < 4; i++) av[i] = Rt[r4 + i][k];
#pragma unroll
    for (int i = 0; i < 4; i++)
#pragma unroll
      for (int j = 0; j < 8; j++) acc[i][j] += av[i] * bv[j];
  }
  float p[4];
#pragma unroll
  for (int i = 0; i < 4; i++) {
    float sum = 0.f;
#pragma unroll
    for (int j = 0; j < 8; j++) sum += acc[i][j] * Rt[r4 + i][c8 + j];
    p[i] = sum;
  }
#pragma unroll
  for (int i = 0; i < 4; i++)
    for (int off = 8; off; off >>= 1) p[i] += __shfl_down(p[i], off, 16);
  if (cg == 0) {
#pragma unroll
    for (int i = 0; i < 4; i++) q11[e0 + r4 + i] = p[i];
  }
}

// ---------------- per-edge logits (wave per edge) + segment max ----------------
__global__ void k_logits(const int* __restrict__ edges, const float* __restrict__ nrep,
                         const float* __restrict__ rel, const float* __restrict__ T,
                         const float* __restrict__ Qv, const double* __restrict__ cq,
                         const float* __restrict__ q11, double* __restrict__ logits,
                         ull* __restrict__ menc) {
  int lane = threadIdx.x & 63;
  int wid = blockIdx.x * (blockDim.x >> 6) + (threadIdx.x >> 6);
  int nw = gridDim.x * (blockDim.x >> 6);
  for (int e = wid; e < EE; e += nw) {
    int eg = edges[(size_t)e * 8 + 0];
    int vi = edges[(size_t)e * 8 + 6];
    int vj = edges[(size_t)e * 8 + 7];
    const float* Tvi = T + (size_t)vi * 384;
    const float* Tvj = T + (size_t)vj * 384;
    const float* q = Qv + (size_t)eg * 384;
    const float* hi = nrep + (size_t)vi * 128;
    const float* hj = nrep + (size_t)vj * 128;
    const float* re = rel + (size_t)e * 128;
    int d0 = lane * 2;
    float2 g   = *(const float2*)&Tvi[d0];
    float2 h1  = *(const float2*)&Tvi[128 + d0];
    float2 jj  = *(const float2*)&Tvj[256 + d0];
    float2 uh  = *(const float2*)&q[d0];
    float2 uiq = *(const float2*)&q[128 + d0];
    float2 urq = *(const float2*)&q[256 + d0];
    float2 hvi = *(const float2*)&hi[d0];
    float2 hvj = *(const float2*)&hj[d0];
    float2 rr  = *(const float2*)&re[d0];
    float v = (g.x + uh.x) * hvj.x + (g.y + uh.y) * hvj.y
            + uiq.x * hvi.x + uiq.y * hvi.y
            + (h1.x + jj.x + urq.x) * rr.x
            + (h1.y + jj.y + urq.y) * rr.y;
    for (int off = 32; off; off >>= 1) v += __shfl_down(v, off, 64);
    if (lane == 0) {
      double l = (double)v + cq[eg] + (double)q11[e];
      logits[e] = l;
      atomicMax(&menc[vi], enc64(l));
    }
  }
}

// ---------------- exp + segment sum (f64) ----------------
__global__ void k_exp(const int* __restrict__ edges, const ull* __restrict__ menc,
                      const double* __restrict__ logits, double* __restrict__ ex,
                      double* __restrict__ s) {
  int i = blockIdx.x * 256 + threadIdx.x;
  int st = gridDim.x * 256;
  for (int e = i; e < EE; e += st) {
    int vi = edges[(size_t)e * 8 + 6];
    double m = dec64(menc[vi]);
    double v = exp(logits[e] - m);
    ex[e] = v;
    atomicAdd(&s[vi], v);
  }
}

__global__ void k_zero_agg(float4* __restrict__ agg) {
  int i = blockIdx.x * 256 + threadIdx.x;
  int st = gridDim.x * 256;
  const int n4 = NN * 32;
  for (int n = i; n < n4; n += st) agg[n] = make_float4(0.f, 0.f, 0.f, 0.f);
}

// ---------------- top-20 per query (lower-index tie-break) + scatter ----------------
__global__ void k_topk(const double* __restrict__ ex, const double* __restrict__ s,
                       const float* __restrict__ nscore, const int* __restrict__ edges,
                       const float* __restrict__ nrep, float* __restrict__ out_score,
                       float* __restrict__ agg, float* __restrict__ appears) {
  int b = blockIdx.x, t = threadIdx.x;  // 256 threads
  int e = b * 256 + t;
  int vi_t = edges[(size_t)e * 8 + 6];
  double v = ex[e] / s[vi_t] * (double)nscore[vi_t];  // target score
  __shared__ double wv[4];
  __shared__ int wi[4];
  __shared__ int winners[KTOP];
  for (int k = 0; k < KTOP; k++) {
    double bv = v;
    int bi = t;
    for (int off = 32; off; off >>= 1) {
      double ov = __shfl_down(bv, off, 64);
      int oi = __shfl_down(bi, off, 64);
      if (ov > bv || (ov == bv && oi < bi)) { bv = ov; bi = oi; }
    }
    if ((t & 63) == 0) { wv[t >> 6] = bv; wi[t >> 6] = bi; }
    __syncthreads();
    if (t == 0) {
      double best = wv[0];
      int besti = wi[0];
      for (int w = 1; w < 4; w++)
        if (wv[w] > best || (wv[w] == best && wi[w] < besti)) { best = wv[w]; besti = wi[w]; }
      winners[k] = besti;
    }
    __syncthreads();
    if (t == winners[k]) v = -1.0;  // targets >= 0
  }
  for (int k = 0; k < KTOP; k++) {
    int we = b * 256 + winners[k];
    int vi = edges[(size_t)we * 8 + 6];
    int vj = edges[(size_t)we * 8 + 7];
    double sm = ex[we] / s[vi];
    if (t < 128) {
      atomicAdd(&agg[(size_t)vi * 128 + t], (float)sm * nrep[(size_t)vj * 128 + t]);
    } else if (t == 128) {
      atomicAdd(&out_score[vj], (float)(sm * (double)nscore[vi]));
    } else if (t == 129) {
      appears[vi] = 1.f;
    }
  }
}

// ---------------- final: leaky_relu((agg + coef*h) @ W_lin^T + b) ----------------
__global__ __launch_bounds__(256, 4) void k_final(const float* __restrict__ agg,
                                                  const float* __restrict__ appears,
                                                  const float* __restrict__ nrep,
                                                  const float* __restrict__ WlT,
                                                  const float* __restrict__ bl,
                                                  float* __restrict__ outr) {
  __shared__ __align__(16) float Xs[64][132];
  int t = threadIdx.x;
  int row0 = blockIdx.x * 64;
#pragma unroll
  for (int i = 0; i < 8; i++) {
    int fi = t + i * 256;
    int r = fi >> 5, c4 = (fi & 31) * 4;
    int rr = row0 + r;
    float4 v = make_float4(0.f, 0.f, 0.f, 0.f);
    if (rr < NN) {
      float4 ag = *(const float4*)(agg + (size_t)rr * 128 + c4);
      float4 h = *(const float4*)(nrep + (size_t)rr * 128 + c4);
      float coef = (appears[rr] > 0.f) ? 0.f : 1.f;  // RATIO = 0
      v.x = ag.x + coef * h.x;
      v.y = ag.y + coef * h.y;
      v.z = ag.z + coef * h.z;
      v.w = ag.w + coef * h.w;
    }
    *(float4*)&Xs[r][c4] = v;
  }
  __syncthreads();
  int cg = t & 15, rg = t >> 4;
  int c8 = cg * 8, r4 = rg * 4;
  const float* Wp = WlT + c8;
  float acc[4][8];
#pragma unroll
  for (int i = 0; i < 4; i++)
#pragma unroll
    for (int j = 0; j < 8; j++) acc[i][j] = 0.f;
#pragma unroll 4
  for (int k = 0; k < 128; k++) {
    float4 b0 = *(const float4*)(Wp + (size_t)k * 128);
    float4 b1 = *(const float4*)(Wp + (size_t)k * 128 + 4);
    float bv[8] = {b0.x, b0.y, b0.z, b0.w, b1.x, b1.y, b1.z, b1.w};
    float av[4];
#pragma unroll
    for (int i = 0; i < 4; i++) av[i] = Xs[r4 + i][k];
#pragma unroll
    for (int i = 0; i < 4; i++)
#pragma unroll
      for (int j = 0; j < 8; j++) acc[i][j] += av[i] * bv[j];
  }
#pragma unroll
  for (int i = 0; i < 4; i++) {
    int r = row0 + r4 + i;
    if (r < NN) {
      float o[8];
#pragma unroll
      for (int j = 0; j < 8; j++) {
        float y = acc[i][j] + bl[c8 + j];
        o[j] = (y > 0.f) ? y : 0.01f * y;
      }
      float* dst = outr + (size_t)r * 128 + c8;
      *(float4*)&dst[0] = *(float4*)&o[0];
      *(float4*)&dst[4] = *(float4*)&o[4];
    }
  }
}

extern "C" void kernel_launch(void* const* d_in, const int* in_sizes, int n_in,
                              void* d_out, int out_size, void* d_ws, size_t ws_size,
                              hipStream_t stream) {
  const float* node_score = (const float*)d_in[0];
  const float* node_repr  = (const float*)d_in[1];
  const float* rel_emb    = (const float*)d_in[2];
  const float* q_src      = (const float*)d_in[3];
  const float* q_rel      = (const float*)d_in[4];
  const float* Wq         = (const float*)d_in[5];
  const float* Wk         = (const float*)d_in[6];
  const float* W_lin      = (const float*)d_in[7];
  const float* b_lin      = (const float*)d_in[8];
  const int*   edges      = (const int*)d_in[9];

  char* ws = (char*)d_ws;
  size_t off = 0;
  auto carve = [&](size_t bytes) -> void* {
    void* p = ws + off;
    off += (bytes + 255) & ~(size_t)255;
    return p;
  };
  float*  M      = (float*)carve(512 * 512 * 4);
  float*  MT     = (float*)carve(512 * 512 * 4);
  float*  Wnode  = (float*)carve(128 * 384 * 4);
  float*  WlT    = (float*)carve(128 * 128 * 4);
  float*  Qv     = (float*)carve((size_t)BQ * 384 * 4);
  double* cq     = (double*)carve((size_t)BQ * 8);
  double* logits = (double*)carve((size_t)EE * 8);
  float*  q11    = (float*)carve((size_t)EE * 4);
  ull*    menc   = (ull*)carve((size_t)NN * 8);
  double* s      = (double*)carve((size_t)NN * 8);
  double* ex     = (double*)carve((size_t)EE * 8);
  float*  appears= (float*)carve((size_t)NN * 4);
  float*  T      = (float*)carve((size_t)NN * 384 * 4);
  float*  agg    = T;  // alias: T dead after k_logits; zeroed by k_zero_agg after

  float* out_score = (float*)d_out;
  float* out_repr  = (float*)d_out + NN;

  k_init<<<512, 256, 0, stream>>>(menc, s, appears, out_score);
  k_matM<<<dim3(512, 2), 256, 0, stream>>>(Wq, Wk, M);
  k_transpose<<<dim3(512, 2), 256, 0, stream>>>(M, MT);
  k_pack<<<256, 256, 0, stream>>>(M, W_lin, Wnode, WlT);
  k_pq<<<BQ, 128, 0, stream>>>(M, MT, q_src, q_rel, Qv, cq);
  k_gemm_node<<<dim3(1563, 3), 256, 0, stream>>>(node_repr, Wnode, T);
  k_q11<<<4096, 256, 0, stream>>>(rel_emb, M, q11);
  k_logits<<<2048, 256, 0, stream>>>(edges, node_repr, rel_emb, T, Qv, cq, q11, logits, menc);
  k_zero_agg<<<2048, 256, 0, stream>>>((float4*)agg);
  k_exp<<<1024, 256, 0, stream>>>(edges, menc, logits, ex, s);
  k_topk<<<BQ, 256, 0, stream>>>(ex, s, node_score, edges, node_repr, out_score, agg, appears);
  k_final<<<1563, 256, 0, stream>>>(agg, appears, node_repr, WlT, b_lin, out_repr);
}